// Round 1
// baseline (176.832 us; speedup 1.0000x reference)
//
#include <hip/hip_runtime.h>
#include <hip/hip_bf16.h>

// Problem constants
constexpr int B  = 4;
constexpr int N  = 10000;
constexpr int E  = 160000;
constexpr int F  = 64;     // F_IN
constexpr int DA = 128;    // D_ATT
constexpr int H  = 8;
constexpr int DK = 16;
constexpr int NCH = 32;    // softmax partial chunks per (b)

__device__ __forceinline__ float bf16lo(unsigned u) {
    u <<= 16;
    return __builtin_bit_cast(float, u);
}
__device__ __forceinline__ float bf16hi(unsigned u) {
    u &= 0xffff0000u;
    return __builtin_bit_cast(float, u);
}
__device__ __forceinline__ unsigned pack_bf16(float a, float b) {
    unsigned ua = __builtin_bit_cast(unsigned, a);
    unsigned ub = __builtin_bit_cast(unsigned, b);
    ua = (ua + 0x7fffu + ((ua >> 16) & 1u)) >> 16;   // RNE
    ub = (ub + 0x7fffu + ((ub >> 16) & 1u)) >> 16;
    return ua | (ub << 16);
}
__device__ __forceinline__ void dotu(unsigned qu, unsigned ku, float& a) {
    a = fmaf(bf16lo(qu), bf16lo(ku), a);
    a = fmaf(bf16hi(qu), bf16hi(ku), a);
}

// ---------------------------------------------------------------------------
// K1: projections. Each block: 64 nodes. thread -> 4 nodes x 8 outputs.
// q,k -> bf16 workspace [m][128]; v -> d_out (f32) at m*128 + d*8 + h.
// ---------------------------------------------------------------------------
__global__ __launch_bounds__(256) void proj_kernel(
    const float* __restrict__ x,
    const float* __restrict__ Qw, const float* __restrict__ Qb,
    const float* __restrict__ Kw, const float* __restrict__ Kb,
    const float* __restrict__ Vw, const float* __restrict__ Vb,
    unsigned short* __restrict__ qws, unsigned short* __restrict__ kws,
    float* __restrict__ vout)
{
    __shared__ float xs[64][68];    // 64 nodes x 64 f, padded (+4) vs bank conflicts
    __shared__ float wl[128][68];   // 128 a x 64 f, padded

    const int t  = threadIdx.x;
    const int m0 = blockIdx.x * 64;

    // stage x tile: 4096 floats as 1024 float4, coalesced
    {
        const float4* src = (const float4*)(x + (size_t)m0 * F);
        #pragma unroll
        for (int k = 0; k < 4; ++k) {
            int i = t + k * 256;
            float4 v = src[i];
            int node = i >> 4, f4 = i & 15;
            *(float4*)&xs[node][f4 * 4] = v;
        }
    }

    const int tn = t & 15;          // node group (16 groups of 4)
    const int ta = t >> 4;          // a group   (16 groups of 8)
    const int nodebase = tn * 4;
    const int a0 = ta * 8;

    for (int mat = 0; mat < 3; ++mat) {
        const float* W    = (mat == 0) ? Qw : (mat == 1) ? Kw : Vw;
        const float* bias = (mat == 0) ? Qb : (mat == 1) ? Kb : Vb;

        __syncthreads();            // protect wl (and xs on first iter)
        {
            const float4* src = (const float4*)W;
            #pragma unroll
            for (int k = 0; k < 8; ++k) {
                int i = t + k * 256;
                float4 v = src[i];
                int row = i >> 4, c4 = i & 15;
                *(float4*)&wl[row][c4 * 4] = v;
            }
        }
        __syncthreads();

        float acc[4][8];
        #pragma unroll
        for (int j = 0; j < 8; ++j) {
            float bb = bias[a0 + j];
            #pragma unroll
            for (int i = 0; i < 4; ++i) acc[i][j] = bb;
        }

        #pragma unroll
        for (int f4 = 0; f4 < 16; ++f4) {
            float4 xv[4], wv[8];
            #pragma unroll
            for (int i = 0; i < 4; ++i) xv[i] = *(const float4*)&xs[nodebase + i][f4 * 4];
            #pragma unroll
            for (int j = 0; j < 8; ++j) wv[j] = *(const float4*)&wl[a0 + j][f4 * 4];
            #pragma unroll
            for (int i = 0; i < 4; ++i) {
                #pragma unroll
                for (int j = 0; j < 8; ++j) {
                    acc[i][j] = fmaf(xv[i].x, wv[j].x, acc[i][j]);
                    acc[i][j] = fmaf(xv[i].y, wv[j].y, acc[i][j]);
                    acc[i][j] = fmaf(xv[i].z, wv[j].z, acc[i][j]);
                    acc[i][j] = fmaf(xv[i].w, wv[j].w, acc[i][j]);
                }
            }
        }

        if (mat < 2) {
            unsigned short* dst = (mat == 0) ? qws : kws;
            #pragma unroll
            for (int i = 0; i < 4; ++i) {
                uint4 p;
                p.x = pack_bf16(acc[i][0], acc[i][1]);
                p.y = pack_bf16(acc[i][2], acc[i][3]);
                p.z = pack_bf16(acc[i][4], acc[i][5]);
                p.w = pack_bf16(acc[i][6], acc[i][7]);
                *(uint4*)(dst + (size_t)(m0 + nodebase + i) * DA + a0) = p;
            }
        } else {
            // a = a0 + j ; h = a>>4 ; d = a&15. a0=ta*8 -> h = ta>>1, d = (ta&1)*8 + j
            const int h  = ta >> 1;
            const int d0 = (ta & 1) * 8;
            #pragma unroll
            for (int i = 0; i < 4; ++i) {
                int m = m0 + nodebase + i;
                float* vb = vout + (size_t)m * DA;   // (b*N+n)*DK*H == m*128
                #pragma unroll
                for (int j = 0; j < 8; ++j) vb[(d0 + j) * H + h] = acc[i][j];
            }
        }
    }
}

// ---------------------------------------------------------------------------
// K2: per (b,e): gather q[src], k[dst] rows (bf16), 8 head-dots of 16.
// Writes raw logits into d_out attention region, layout [b][e][h].
// ---------------------------------------------------------------------------
__global__ __launch_bounds__(256) void gather_dot(
    const unsigned short* __restrict__ qws, const unsigned short* __restrict__ kws,
    const int* __restrict__ edge, float* __restrict__ att)
{
    int idx = blockIdx.x * 256 + threadIdx.x;    // [0, B*E) exactly
    int b = idx / E;
    int e = idx - b * E;
    int s = edge[e];          // edge[0][e]
    int d = edge[E + e];      // edge[1][e]

    const uint4* qp = (const uint4*)(qws + ((size_t)b * N + s) * DA);
    const uint4* kp = (const uint4*)(kws + ((size_t)b * N + d) * DA);

    float o[8];
    #pragma unroll
    for (int h = 0; h < 8; ++h) {
        uint4 qa = qp[2 * h], qb2 = qp[2 * h + 1];
        uint4 ka = kp[2 * h], kb2 = kp[2 * h + 1];
        float a = 0.f;
        dotu(qa.x, ka.x, a);  dotu(qa.y, ka.y, a);
        dotu(qa.z, ka.z, a);  dotu(qa.w, ka.w, a);
        dotu(qb2.x, kb2.x, a); dotu(qb2.y, kb2.y, a);
        dotu(qb2.z, kb2.z, a); dotu(qb2.w, kb2.w, a);
        o[h] = a * 0.25f;     // 1/sqrt(16)
    }
    float* op = att + (size_t)idx * H;
    *(float4*)op       = make_float4(o[0], o[1], o[2], o[3]);
    *(float4*)(op + 4) = make_float4(o[4], o[5], o[6], o[7]);
}

// ---------------------------------------------------------------------------
// K3: per (b, chunk): online (max,sum) partials per h. thread-fixed h = t&7
// keeps reads contiguous and state in scalars.
// ---------------------------------------------------------------------------
__global__ __launch_bounds__(256) void softmax_part(
    const float* __restrict__ att, float2* __restrict__ partials)
{
    const int b = blockIdx.y, ch = blockIdx.x, t = threadIdx.x;
    const float* base = att + (size_t)b * (E * H);
    const int per_chunk = (E * H) / NCH;          // 40000, %8==0 so h=t&7 stable
    int i   = ch * per_chunk + t;
    int end = (ch + 1) * per_chunk;

    float m = -3.0e38f, s = 0.f;
    for (; i < end; i += 256) {
        float p = base[i];
        if (p > m) { s = s * __expf(m - p) + 1.f; m = p; }
        else       { s += __expf(p - m); }
    }

    __shared__ float sm[256], ss[256];
    sm[t] = m; ss[t] = s;
    __syncthreads();
    for (int off = 128; off >= 8; off >>= 1) {
        if (t < off) {
            float m1 = sm[t], s1 = ss[t];
            float m2 = sm[t + off], s2 = ss[t + off];
            float M = fmaxf(m1, m2);
            sm[t] = M;
            ss[t] = s1 * __expf(m1 - M) + s2 * __expf(m2 - M);
        }
        __syncthreads();
    }
    if (t < 8) partials[((size_t)b * H + t) * NCH + ch] = make_float2(sm[t], ss[t]);
}

// ---------------------------------------------------------------------------
// K4: combine NCH partials per (b,h) -> (M, 1/S)
// ---------------------------------------------------------------------------
__global__ void softmax_final(const float2* __restrict__ partials,
                              float2* __restrict__ MS)
{
    int t = threadIdx.x;
    if (t >= B * H) return;
    float m = -3.0e38f, s = 0.f;
    for (int c = 0; c < NCH; ++c) {
        float2 p = partials[t * NCH + c];
        float M = fmaxf(m, p.x);
        s = s * __expf(m - M) + p.y * __expf(p.x - M);
        m = M;
    }
    MS[t] = make_float2(m, 1.0f / s);
}

// ---------------------------------------------------------------------------
// K5: in-place normalize: att = exp(p - M) * (1/S)
// ---------------------------------------------------------------------------
__global__ __launch_bounds__(256) void softmax_norm(
    float* __restrict__ att, const float2* __restrict__ MS)
{
    int idx = blockIdx.x * 256 + threadIdx.x;    // float4 index, B*E*H/4 total
    float4 p = ((const float4*)att)[idx];
    int b = idx / ((E * H) / 4);                 // 320000
    const float2* ms = MS + b * H + (idx & 1) * 4;
    p.x = __expf(p.x - ms[0].x) * ms[0].y;
    p.y = __expf(p.y - ms[1].x) * ms[1].y;
    p.z = __expf(p.z - ms[2].x) * ms[2].y;
    p.w = __expf(p.w - ms[3].x) * ms[3].y;
    ((float4*)att)[idx] = p;
}

extern "C" void kernel_launch(void* const* d_in, const int* in_sizes, int n_in,
                              void* d_out, int out_size, void* d_ws, size_t ws_size,
                              hipStream_t stream)
{
    const float* x  = (const float*)d_in[0];
    const float* Qw = (const float*)d_in[1];
    const float* Qb = (const float*)d_in[2];
    const float* Kw = (const float*)d_in[3];
    const float* Kb = (const float*)d_in[4];
    const float* Vw = (const float*)d_in[5];
    const float* Vb = (const float*)d_in[6];
    const int*   edge = (const int*)d_in[7];

    float* out  = (float*)d_out;
    float* att  = out;                                // B*E*H
    float* vout = out + (size_t)B * E * H;            // B*N*DK*H

    char* w = (char*)d_ws;
    unsigned short* qws = (unsigned short*)w;                       // 10.24 MB
    unsigned short* kws = qws + (size_t)B * N * DA;                 // 10.24 MB
    float2* partials = (float2*)(w + 2 * (size_t)B * N * DA * 2);   // 8 KB
    float2* MS = partials + B * H * NCH;

    hipLaunchKernelGGL(proj_kernel, dim3((B * N) / 64), dim3(256), 0, stream,
                       x, Qw, Qb, Kw, Kb, Vw, Vb, qws, kws, vout);
    hipLaunchKernelGGL(gather_dot, dim3((B * E) / 256), dim3(256), 0, stream,
                       qws, kws, edge, att);
    hipLaunchKernelGGL(softmax_part, dim3(NCH, B), dim3(256), 0, stream,
                       att, partials);
    hipLaunchKernelGGL(softmax_final, dim3(1), dim3(64), 0, stream,
                       partials, MS);
    hipLaunchKernelGGL(softmax_norm, dim3((B * E * H / 4) / 256), dim3(256), 0, stream,
                       att, MS);
}

// Round 2
// 143.448 us; speedup vs baseline: 1.2327x; 1.2327x over previous
//
#include <hip/hip_runtime.h>
#include <hip/hip_bf16.h>

// Problem constants
constexpr int B  = 4;
constexpr int N  = 10000;
constexpr int E  = 160000;
constexpr int F  = 64;     // F_IN
constexpr int DA = 128;    // D_ATT
constexpr int H  = 8;
constexpr int DK = 16;
constexpr int NCH = 32;    // softmax partial chunks per (b)
constexpr int TOTAL = B * N;   // 40000 rows

typedef __attribute__((ext_vector_type(8))) short short8v;  // 8 bf16 (4 VGPRs)
typedef __attribute__((ext_vector_type(4))) float f32x4;

__device__ __forceinline__ float bf16lo(unsigned u) {
    u <<= 16;
    return __builtin_bit_cast(float, u);
}
__device__ __forceinline__ float bf16hi(unsigned u) {
    u &= 0xffff0000u;
    return __builtin_bit_cast(float, u);
}
__device__ __forceinline__ unsigned pack_bf16(float a, float b) {
    unsigned ua = __builtin_bit_cast(unsigned, a);
    unsigned ub = __builtin_bit_cast(unsigned, b);
    ua = (ua + 0x7fffu + ((ua >> 16) & 1u)) >> 16;   // RNE
    ub = (ub + 0x7fffu + ((ub >> 16) & 1u)) >> 16;
    return ua | (ub << 16);
}
__device__ __forceinline__ void dot2(unsigned qu, unsigned ku, float& alo, float& ahi) {
    alo = fmaf(bf16lo(qu), bf16lo(ku), alo);
    ahi = fmaf(bf16hi(qu), bf16hi(ku), ahi);
}
__device__ __forceinline__ short8v cvt8(float4 a, float4 b) {
    union { unsigned u[4]; short8v s; } r;
    r.u[0] = pack_bf16(a.x, a.y);
    r.u[1] = pack_bf16(a.z, a.w);
    r.u[2] = pack_bf16(b.x, b.y);
    r.u[3] = pack_bf16(b.z, b.w);
    return r.s;
}

// ---------------------------------------------------------------------------
// K1: MFMA projections. grid = (313 node-blocks, 3 matrices).
// Block = 4 waves; each wave: 16 W-frags in regs, loop 16-node tiles.
// A-frag: lane&15 = node row, k = (lane>>4)*8+j  (16B contiguous per lane)
// B-frag: lane&15 = output col a, same k layout
// D: col a = a0t*16 + (lane&15), node row = (lane>>4)*4 + reg
// q/k ws layout and v out layout: p = d*8 + h  (head-transposed) -> lane's
// 8 cols (a0t=0..7 at fixed tn) are CONTIGUOUS positions tn*8..tn*8+7.
// ---------------------------------------------------------------------------
__global__ __launch_bounds__(256) void proj_mfma(
    const float* __restrict__ x,
    const float* __restrict__ Qw, const float* __restrict__ Qb,
    const float* __restrict__ Kw, const float* __restrict__ Kb,
    const float* __restrict__ Vw, const float* __restrict__ Vb,
    unsigned short* __restrict__ qws, unsigned short* __restrict__ kws,
    float* __restrict__ vout)
{
    const int t    = threadIdx.x;
    const int w    = t >> 6;        // wave 0..3
    const int lane = t & 63;
    const int tn   = lane & 15;
    const int g    = lane >> 4;     // 0..3

    const int mat = blockIdx.y;
    const float* W    = (mat == 0) ? Qw : (mat == 1) ? Kw : Vw;
    const float* bias = (mat == 0) ? Qb : (mat == 1) ? Kb : Vb;
    unsigned short* qk_dst = (mat == 0) ? qws : kws;

    // --- load 16 B-frags (all 8 col-tiles x 2 k-tiles) into registers ---
    short8v bf[8][2];
    float bv[8];
    #pragma unroll
    for (int a0t = 0; a0t < 8; ++a0t) {
        bv[a0t] = bias[a0t * 16 + tn];
        const float4* wr = (const float4*)(W + (size_t)(a0t * 16 + tn) * F);
        bf[a0t][0] = cvt8(wr[g * 2],     wr[g * 2 + 1]);
        bf[a0t][1] = cvt8(wr[8 + g * 2], wr[8 + g * 2 + 1]);
    }

    #pragma unroll
    for (int rt = 0; rt < 2; ++rt) {
        const int m0t = blockIdx.x * 128 + rt * 64 + w * 16;
        if (m0t >= TOTAL) break;

        // A-frags for this 16-node tile
        const float4* xr = (const float4*)(x + (size_t)(m0t + tn) * F);
        short8v a0 = cvt8(xr[g * 2],     xr[g * 2 + 1]);
        short8v a1 = cvt8(xr[8 + g * 2], xr[8 + g * 2 + 1]);

        f32x4 acc[8];
        #pragma unroll
        for (int a0t = 0; a0t < 8; ++a0t) {
            acc[a0t][0] = bv[a0t]; acc[a0t][1] = bv[a0t];
            acc[a0t][2] = bv[a0t]; acc[a0t][3] = bv[a0t];
        }
        #pragma unroll
        for (int a0t = 0; a0t < 8; ++a0t) {
            acc[a0t] = __builtin_amdgcn_mfma_f32_16x16x32_bf16(a0, bf[a0t][0], acc[a0t], 0, 0, 0);
            acc[a0t] = __builtin_amdgcn_mfma_f32_16x16x32_bf16(a1, bf[a0t][1], acc[a0t], 0, 0, 0);
        }

        if (mat < 2) {
            #pragma unroll
            for (int r = 0; r < 4; ++r) {
                const int node = m0t + g * 4 + r;
                uint4 pk;
                pk.x = pack_bf16(acc[0][r], acc[1][r]);
                pk.y = pack_bf16(acc[2][r], acc[3][r]);
                pk.z = pack_bf16(acc[4][r], acc[5][r]);
                pk.w = pack_bf16(acc[6][r], acc[7][r]);
                *(uint4*)(qk_dst + (size_t)node * DA + tn * 8) = pk;
            }
        } else {
            #pragma unroll
            for (int r = 0; r < 4; ++r) {
                const int node = m0t + g * 4 + r;
                float* vb = vout + (size_t)node * DA + tn * 8;
                *(float4*)vb       = make_float4(acc[0][r], acc[1][r], acc[2][r], acc[3][r]);
                *(float4*)(vb + 4) = make_float4(acc[4][r], acc[5][r], acc[6][r], acc[7][r]);
            }
        }
    }
}

// ---------------------------------------------------------------------------
// K2: per (b,e): gather q[src], k[dst] rows (bf16, head-transposed layout
// p = d*8+h), 8 head-dots. Word u = i*4+c covers positions 8i+2c, 8i+2c+1
// -> heads 2c, 2c+1 (independent of i).
// ---------------------------------------------------------------------------
__global__ __launch_bounds__(256) void gather_dot(
    const unsigned short* __restrict__ qws, const unsigned short* __restrict__ kws,
    const int* __restrict__ edge, float* __restrict__ att)
{
    int idx = blockIdx.x * 256 + threadIdx.x;    // [0, B*E)
    int b = idx / E;
    int e = idx - b * E;
    int s = edge[e];          // edge[0][e]
    int d = edge[E + e];      // edge[1][e]

    const uint4* qp = (const uint4*)(qws + ((size_t)b * N + s) * DA);
    const uint4* kp = (const uint4*)(kws + ((size_t)b * N + d) * DA);

    float o[8] = {0.f, 0.f, 0.f, 0.f, 0.f, 0.f, 0.f, 0.f};
    #pragma unroll
    for (int i = 0; i < 16; ++i) {
        uint4 qa = qp[i], ka = kp[i];
        dot2(qa.x, ka.x, o[0], o[1]);
        dot2(qa.y, ka.y, o[2], o[3]);
        dot2(qa.z, ka.z, o[4], o[5]);
        dot2(qa.w, ka.w, o[6], o[7]);
    }
    float* op = att + (size_t)idx * H;
    *(float4*)op       = make_float4(o[0] * 0.25f, o[1] * 0.25f, o[2] * 0.25f, o[3] * 0.25f);
    *(float4*)(op + 4) = make_float4(o[4] * 0.25f, o[5] * 0.25f, o[6] * 0.25f, o[7] * 0.25f);
}

// ---------------------------------------------------------------------------
// K3: per (b, chunk): online (max,sum) partials per h (h = t&7 fixed).
// ---------------------------------------------------------------------------
__global__ __launch_bounds__(256) void softmax_part(
    const float* __restrict__ att, float2* __restrict__ partials)
{
    const int b = blockIdx.y, ch = blockIdx.x, t = threadIdx.x;
    const float* base = att + (size_t)b * (E * H);
    const int per_chunk = (E * H) / NCH;          // 40000, %8==0 so h=t&7 stable
    int i   = ch * per_chunk + t;
    int end = (ch + 1) * per_chunk;

    float m = -3.0e38f, s = 0.f;
    for (; i < end; i += 256) {
        float p = base[i];
        if (p > m) { s = s * __expf(m - p) + 1.f; m = p; }
        else       { s += __expf(p - m); }
    }

    __shared__ float sm[256], ss[256];
    sm[t] = m; ss[t] = s;
    __syncthreads();
    for (int off = 128; off >= 8; off >>= 1) {
        if (t < off) {
            float m1 = sm[t], s1 = ss[t];
            float m2 = sm[t + off], s2 = ss[t + off];
            float M = fmaxf(m1, m2);
            sm[t] = M;
            ss[t] = s1 * __expf(m1 - M) + s2 * __expf(m2 - M);
        }
        __syncthreads();
    }
    if (t < 8) partials[((size_t)b * H + t) * NCH + ch] = make_float2(sm[t], ss[t]);
}

// ---------------------------------------------------------------------------
// K4: combine NCH partials per (b,h) -> (M, 1/S)
// ---------------------------------------------------------------------------
__global__ void softmax_final(const float2* __restrict__ partials,
                              float2* __restrict__ MS)
{
    int t = threadIdx.x;
    if (t >= B * H) return;
    float m = -3.0e38f, s = 0.f;
    for (int c = 0; c < NCH; ++c) {
        float2 p = partials[t * NCH + c];
        float M = fmaxf(m, p.x);
        s = s * __expf(m - M) + p.y * __expf(p.x - M);
        m = M;
    }
    MS[t] = make_float2(m, 1.0f / s);
}

// ---------------------------------------------------------------------------
// K5: in-place normalize: att = exp(p - M) * (1/S)
// ---------------------------------------------------------------------------
__global__ __launch_bounds__(256) void softmax_norm(
    float* __restrict__ att, const float2* __restrict__ MS)
{
    int idx = blockIdx.x * 256 + threadIdx.x;    // float4 index, B*E*H/4 total
    float4 p = ((const float4*)att)[idx];
    int b = idx / ((E * H) / 4);                 // 320000
    const float2* ms = MS + b * H + (idx & 1) * 4;
    p.x = __expf(p.x - ms[0].x) * ms[0].y;
    p.y = __expf(p.y - ms[1].x) * ms[1].y;
    p.z = __expf(p.z - ms[2].x) * ms[2].y;
    p.w = __expf(p.w - ms[3].x) * ms[3].y;
    ((float4*)att)[idx] = p;
}

extern "C" void kernel_launch(void* const* d_in, const int* in_sizes, int n_in,
                              void* d_out, int out_size, void* d_ws, size_t ws_size,
                              hipStream_t stream)
{
    const float* x  = (const float*)d_in[0];
    const float* Qw = (const float*)d_in[1];
    const float* Qb = (const float*)d_in[2];
    const float* Kw = (const float*)d_in[3];
    const float* Kb = (const float*)d_in[4];
    const float* Vw = (const float*)d_in[5];
    const float* Vb = (const float*)d_in[6];
    const int*   edge = (const int*)d_in[7];

    float* out  = (float*)d_out;
    float* att  = out;                                // B*E*H
    float* vout = out + (size_t)B * E * H;            // B*N*DK*H

    char* w = (char*)d_ws;
    unsigned short* qws = (unsigned short*)w;                       // 10.24 MB
    unsigned short* kws = qws + (size_t)B * N * DA;                 // 10.24 MB
    float2* partials = (float2*)(w + 2 * (size_t)B * N * DA * 2);   // 8 KB
    float2* MS = partials + B * H * NCH;

    hipLaunchKernelGGL(proj_mfma, dim3((TOTAL + 127) / 128, 3), dim3(256), 0, stream,
                       x, Qw, Qb, Kw, Kb, Vw, Vb, qws, kws, vout);
    hipLaunchKernelGGL(gather_dot, dim3((B * E) / 256), dim3(256), 0, stream,
                       qws, kws, edge, att);
    hipLaunchKernelGGL(softmax_part, dim3(NCH, B), dim3(256), 0, stream,
                       att, partials);
    hipLaunchKernelGGL(softmax_final, dim3(1), dim3(64), 0, stream,
                       partials, MS);
    hipLaunchKernelGGL(softmax_norm, dim3((B * E * H / 4) / 256), dim3(256), 0, stream,
                       att, MS);
}

// Round 3
// 83.034 us; speedup vs baseline: 2.1296x; 1.7276x over previous
//
#include <hip/hip_runtime.h>
#include <hip/hip_bf16.h>

// Problem constants
constexpr int B  = 4;
constexpr int N  = 10000;
constexpr int E  = 160000;
constexpr int F  = 64;     // F_IN
constexpr int DA = 128;    // D_ATT
constexpr int H  = 8;
constexpr int DK = 16;
constexpr int TOTAL = B * N;   // 40000 rows

constexpr int EPB  = 1024;                  // edges per block (gather)
constexpr int NBLK = (E + EPB - 1) / EPB;   // 157 blocks per b

typedef __attribute__((ext_vector_type(8))) short short8v;  // 8 bf16 (4 VGPRs)
typedef __attribute__((ext_vector_type(4))) float f32x4;

__device__ __forceinline__ float bf16lo(unsigned u) {
    u <<= 16;
    return __builtin_bit_cast(float, u);
}
__device__ __forceinline__ float bf16hi(unsigned u) {
    u &= 0xffff0000u;
    return __builtin_bit_cast(float, u);
}
__device__ __forceinline__ unsigned pack_bf16(float a, float b) {
    unsigned ua = __builtin_bit_cast(unsigned, a);
    unsigned ub = __builtin_bit_cast(unsigned, b);
    ua = (ua + 0x7fffu + ((ua >> 16) & 1u)) >> 16;   // RNE
    ub = (ub + 0x7fffu + ((ub >> 16) & 1u)) >> 16;
    return ua | (ub << 16);
}
__device__ __forceinline__ void dot2(unsigned qu, unsigned ku, float& alo, float& ahi) {
    alo = fmaf(bf16lo(qu), bf16lo(ku), alo);
    ahi = fmaf(bf16hi(qu), bf16hi(ku), ahi);
}
__device__ __forceinline__ void dotq(uint4 q, uint4 k, float* o) {
    dot2(q.x, k.x, o[0], o[1]);
    dot2(q.y, k.y, o[2], o[3]);
    dot2(q.z, k.z, o[4], o[5]);
    dot2(q.w, k.w, o[6], o[7]);
}
__device__ __forceinline__ short8v cvt8(float4 a, float4 b) {
    union { unsigned u[4]; short8v s; } r;
    r.u[0] = pack_bf16(a.x, a.y);
    r.u[1] = pack_bf16(a.z, a.w);
    r.u[2] = pack_bf16(b.x, b.y);
    r.u[3] = pack_bf16(b.z, b.w);
    return r.s;
}
__device__ __forceinline__ void ocomb(float& m, float& s, float m2, float s2) {
    float M = fmaxf(m, m2);
    s = s * __expf(m - M) + s2 * __expf(m2 - M);
    m = M;
}

// ---------------------------------------------------------------------------
// K1: MFMA projections. grid = (313 node-blocks, 3 matrices).
// q/k ws layout and v out layout: p = d*8 + h (head-transposed).
// ---------------------------------------------------------------------------
__global__ __launch_bounds__(256) void proj_mfma(
    const float* __restrict__ x,
    const float* __restrict__ Qw, const float* __restrict__ Qb,
    const float* __restrict__ Kw, const float* __restrict__ Kb,
    const float* __restrict__ Vw, const float* __restrict__ Vb,
    unsigned short* __restrict__ qws, unsigned short* __restrict__ kws,
    float* __restrict__ vout)
{
    const int t    = threadIdx.x;
    const int w    = t >> 6;        // wave 0..3
    const int lane = t & 63;
    const int tn   = lane & 15;
    const int g    = lane >> 4;     // 0..3

    const int mat = blockIdx.y;
    const float* W    = (mat == 0) ? Qw : (mat == 1) ? Kw : Vw;
    const float* bias = (mat == 0) ? Qb : (mat == 1) ? Kb : Vb;
    unsigned short* qk_dst = (mat == 0) ? qws : kws;

    short8v bf[8][2];
    float bv[8];
    #pragma unroll
    for (int a0t = 0; a0t < 8; ++a0t) {
        bv[a0t] = bias[a0t * 16 + tn];
        const float4* wr = (const float4*)(W + (size_t)(a0t * 16 + tn) * F);
        bf[a0t][0] = cvt8(wr[g * 2],     wr[g * 2 + 1]);
        bf[a0t][1] = cvt8(wr[8 + g * 2], wr[8 + g * 2 + 1]);
    }

    #pragma unroll
    for (int rt = 0; rt < 2; ++rt) {
        const int m0t = blockIdx.x * 128 + rt * 64 + w * 16;
        if (m0t >= TOTAL) break;

        const float4* xr = (const float4*)(x + (size_t)(m0t + tn) * F);
        short8v a0 = cvt8(xr[g * 2],     xr[g * 2 + 1]);
        short8v a1 = cvt8(xr[8 + g * 2], xr[8 + g * 2 + 1]);

        f32x4 acc[8];
        #pragma unroll
        for (int a0t = 0; a0t < 8; ++a0t) {
            acc[a0t][0] = bv[a0t]; acc[a0t][1] = bv[a0t];
            acc[a0t][2] = bv[a0t]; acc[a0t][3] = bv[a0t];
        }
        #pragma unroll
        for (int a0t = 0; a0t < 8; ++a0t) {
            acc[a0t] = __builtin_amdgcn_mfma_f32_16x16x32_bf16(a0, bf[a0t][0], acc[a0t], 0, 0, 0);
            acc[a0t] = __builtin_amdgcn_mfma_f32_16x16x32_bf16(a1, bf[a0t][1], acc[a0t], 0, 0, 0);
        }

        if (mat < 2) {
            #pragma unroll
            for (int r = 0; r < 4; ++r) {
                const int node = m0t + g * 4 + r;
                uint4 pk;
                pk.x = pack_bf16(acc[0][r], acc[1][r]);
                pk.y = pack_bf16(acc[2][r], acc[3][r]);
                pk.z = pack_bf16(acc[4][r], acc[5][r]);
                pk.w = pack_bf16(acc[6][r], acc[7][r]);
                *(uint4*)(qk_dst + (size_t)node * DA + tn * 8) = pk;
            }
        } else {
            #pragma unroll
            for (int r = 0; r < 4; ++r) {
                const int node = m0t + g * 4 + r;
                float* vb = vout + (size_t)node * DA + tn * 8;
                *(float4*)vb       = make_float4(acc[0][r], acc[1][r], acc[2][r], acc[3][r]);
                *(float4*)(vb + 4) = make_float4(acc[4][r], acc[5][r], acc[6][r], acc[7][r]);
            }
        }
    }
}

// ---------------------------------------------------------------------------
// K2: cooperative gather + dot + fused softmax partials.
// 4 lanes per edge; lane i holds d-slices {i, i+4, i+8, i+12} (one 64B line
// per 4-lane group per load instr). 2-level shfl_xor gives per-head sums.
// Each lane online-tracks (m,s) for heads {2i, 2i+1}; block partials out.
// grid = (B, NBLK) so linear block id % 4 == b -> per-XCD L2 sees one b.
// ---------------------------------------------------------------------------
__global__ __launch_bounds__(256) void gather_dot_sm(
    const unsigned short* __restrict__ qws, const unsigned short* __restrict__ kws,
    const int* __restrict__ edge, float* __restrict__ att,
    float2* __restrict__ partials)
{
    const int b   = blockIdx.x;
    const int blk = blockIdx.y;
    const int t = threadIdx.x;
    const int w = t >> 6, lane = t & 63;
    const int g = lane >> 2, i = lane & 3;

    const unsigned short* qb = qws + (size_t)b * N * DA;
    const unsigned short* kb = kws + (size_t)b * N * DA;
    float* attb = att + (size_t)b * E * H;

    const int ew0 = blk * EPB + w * (EPB / 4);   // wave's edge base

    float ma0 = -3.0e38f, sa0 = 0.f, ma1 = -3.0e38f, sa1 = 0.f;

    #pragma unroll 1
    for (int r = 0; r < EPB / 4 / 16; ++r) {     // 16 rounds of 16 edges
        const int el = ew0 + r * 16 + g;
        const bool valid = el < E;
        const int eidx = valid ? el : 0;
        const int s = edge[eidx];
        const int d = edge[E + eidx];
        const uint4* qp = (const uint4*)(qb + (size_t)s * DA) + i;
        const uint4* kp = (const uint4*)(kb + (size_t)d * DA) + i;
        uint4 q0 = qp[0], q1 = qp[4], q2 = qp[8], q3 = qp[12];
        uint4 k0 = kp[0], k1 = kp[4], k2 = kp[8], k3 = kp[12];

        float o[8] = {0.f, 0.f, 0.f, 0.f, 0.f, 0.f, 0.f, 0.f};
        dotq(q0, k0, o); dotq(q1, k1, o); dotq(q2, k2, o); dotq(q3, k3, o);

        #pragma unroll
        for (int h2 = 0; h2 < 8; ++h2) o[h2] += __shfl_xor(o[h2], 1);
        #pragma unroll
        for (int h2 = 0; h2 < 8; ++h2) o[h2] += __shfl_xor(o[h2], 2);
        #pragma unroll
        for (int h2 = 0; h2 < 8; ++h2) o[h2] *= 0.25f;

        if (i == 0 && valid) {
            float* op = attb + (size_t)el * H;
            *(float4*)op       = make_float4(o[0], o[1], o[2], o[3]);
            *(float4*)(op + 4) = make_float4(o[4], o[5], o[6], o[7]);
        }
        if (valid) {
            float p0 = (i == 0) ? o[0] : (i == 1) ? o[2] : (i == 2) ? o[4] : o[6];
            float p1 = (i == 0) ? o[1] : (i == 1) ? o[3] : (i == 2) ? o[5] : o[7];
            if (p0 > ma0) { sa0 = sa0 * __expf(ma0 - p0) + 1.f; ma0 = p0; }
            else          { sa0 += __expf(p0 - ma0); }
            if (p1 > ma1) { sa1 = sa1 * __expf(ma1 - p1) + 1.f; ma1 = p1; }
            else          { sa1 += __expf(p1 - ma1); }
        }
    }

    // wave-level combine across the 16 groups (lanes with equal i)
    #pragma unroll
    for (int off = 4; off <= 32; off <<= 1) {
        float m2 = __shfl_xor(ma0, off), s2 = __shfl_xor(sa0, off);
        ocomb(ma0, sa0, m2, s2);
        m2 = __shfl_xor(ma1, off); s2 = __shfl_xor(sa1, off);
        ocomb(ma1, sa1, m2, s2);
    }

    __shared__ float4 red[4][4];
    if (g == 0) red[w][i] = make_float4(ma0, sa0, ma1, sa1);
    __syncthreads();
    if (t < 4) {
        float m0f = -3.0e38f, s0f = 0.f, m1f = -3.0e38f, s1f = 0.f;
        #pragma unroll
        for (int ww = 0; ww < 4; ++ww) {
            float4 v = red[ww][t];
            ocomb(m0f, s0f, v.x, v.y);
            ocomb(m1f, s1f, v.z, v.w);
        }
        partials[((size_t)b * H + 2 * t)     * NBLK + blk] = make_float2(m0f, s0f);
        partials[((size_t)b * H + 2 * t + 1) * NBLK + blk] = make_float2(m1f, s1f);
    }
}

// ---------------------------------------------------------------------------
// K4: combine NBLK partials per (b,h) -> (M, 1/S)
// ---------------------------------------------------------------------------
__global__ void softmax_final(const float2* __restrict__ partials,
                              float2* __restrict__ MS)
{
    int t = threadIdx.x;
    if (t >= B * H) return;
    float m = -3.0e38f, s = 0.f;
    for (int c = 0; c < NBLK; ++c) {
        float2 p = partials[(size_t)t * NBLK + c];
        ocomb(m, s, p.x, p.y);
    }
    MS[t] = make_float2(m, 1.0f / s);
}

// ---------------------------------------------------------------------------
// K5: in-place normalize: att = exp(p - M) * (1/S)
// ---------------------------------------------------------------------------
__global__ __launch_bounds__(256) void softmax_norm(
    float* __restrict__ att, const float2* __restrict__ MS)
{
    int idx = blockIdx.x * 256 + threadIdx.x;    // float4 index, B*E*H/4 total
    float4 p = ((const float4*)att)[idx];
    int b = idx / ((E * H) / 4);                 // 320000
    const float2* ms = MS + b * H + (idx & 1) * 4;
    p.x = __expf(p.x - ms[0].x) * ms[0].y;
    p.y = __expf(p.y - ms[1].x) * ms[1].y;
    p.z = __expf(p.z - ms[2].x) * ms[2].y;
    p.w = __expf(p.w - ms[3].x) * ms[3].y;
    ((float4*)att)[idx] = p;
}

extern "C" void kernel_launch(void* const* d_in, const int* in_sizes, int n_in,
                              void* d_out, int out_size, void* d_ws, size_t ws_size,
                              hipStream_t stream)
{
    const float* x  = (const float*)d_in[0];
    const float* Qw = (const float*)d_in[1];
    const float* Qb = (const float*)d_in[2];
    const float* Kw = (const float*)d_in[3];
    const float* Kb = (const float*)d_in[4];
    const float* Vw = (const float*)d_in[5];
    const float* Vb = (const float*)d_in[6];
    const int*   edge = (const int*)d_in[7];

    float* out  = (float*)d_out;
    float* att  = out;                                // B*E*H
    float* vout = out + (size_t)B * E * H;            // B*N*DK*H

    char* w = (char*)d_ws;
    unsigned short* qws = (unsigned short*)w;                       // 10.24 MB
    unsigned short* kws = qws + (size_t)B * N * DA;                 // 10.24 MB
    float2* partials = (float2*)(w + 2 * (size_t)B * N * DA * 2);   // ~40 KB
    float2* MS = partials + (size_t)B * H * NBLK;

    hipLaunchKernelGGL(proj_mfma, dim3((TOTAL + 127) / 128, 3), dim3(256), 0, stream,
                       x, Qw, Qb, Kw, Kb, Vw, Vb, qws, kws, vout);
    hipLaunchKernelGGL(gather_dot_sm, dim3(B, NBLK), dim3(256), 0, stream,
                       qws, kws, edge, att, partials);
    hipLaunchKernelGGL(softmax_final, dim3(1), dim3(64), 0, stream,
                       partials, MS);
    hipLaunchKernelGGL(softmax_norm, dim3((B * E * H / 4) / 256), dim3(256), 0, stream,
                       att, MS);
}

// Round 4
// 58.172 us; speedup vs baseline: 3.0398x; 1.4274x over previous
//
#include <hip/hip_runtime.h>
#include <hip/hip_bf16.h>

// Problem constants
constexpr int B  = 4;
constexpr int N  = 10000;
constexpr int E  = 160000;
constexpr int F  = 64;     // F_IN
constexpr int DA = 128;    // D_ATT
constexpr int H  = 8;
constexpr int DK = 16;
constexpr int TOTAL = B * N;   // 40000 rows

constexpr int EPB  = 512;                   // edges per block (gather)
constexpr int NBLK = (E + EPB - 1) / EPB;   // 313 blocks per b

typedef __attribute__((ext_vector_type(8))) short short8v;  // 8 bf16 (4 VGPRs)
typedef __attribute__((ext_vector_type(4))) float f32x4;
typedef __attribute__((ext_vector_type(2))) float f32x2;

__device__ __forceinline__ unsigned pack_bf16(float a, float b) {
    unsigned ua = __builtin_bit_cast(unsigned, a);
    unsigned ub = __builtin_bit_cast(unsigned, b);
    ua = (ua + 0x7fffu + ((ua >> 16) & 1u)) >> 16;   // RNE
    ub = (ub + 0x7fffu + ((ub >> 16) & 1u)) >> 16;
    return ua | (ub << 16);
}
__device__ __forceinline__ short8v cvt8(float4 a, float4 b) {
    union { unsigned u[4]; short8v s; } r;
    r.u[0] = pack_bf16(a.x, a.y);
    r.u[1] = pack_bf16(a.z, a.w);
    r.u[2] = pack_bf16(b.x, b.y);
    r.u[3] = pack_bf16(b.z, b.w);
    return r.s;
}
__device__ __forceinline__ void ocomb(float& m, float& s, float m2, float s2) {
    float M = fmaxf(m, m2);
    s = s * __expf(m - M) + s2 * __expf(m2 - M);
    m = M;
}
// q,k dwords = 4 fp8 covering 4 consecutive heads; accumulate into two f32x2.
__device__ __forceinline__ void fp8dot(unsigned q, unsigned k, f32x2& olo, f32x2& ohi) {
    f32x2 ql = __builtin_amdgcn_cvt_pk_f32_fp8((int)q, false);
    f32x2 qh = __builtin_amdgcn_cvt_pk_f32_fp8((int)q, true);
    f32x2 kl = __builtin_amdgcn_cvt_pk_f32_fp8((int)k, false);
    f32x2 kh = __builtin_amdgcn_cvt_pk_f32_fp8((int)k, true);
    olo += ql * kl;
    ohi += qh * kh;
}

// ---------------------------------------------------------------------------
// K1: MFMA projections. grid = (313 node-blocks, 3 matrices).
// Layout p = d*8 + h (head-transposed). q/k stored as fp8 e4m3 (q pre-scaled
// by 1/sqrt(DK)); v stored f32 to d_out.
// ---------------------------------------------------------------------------
__global__ __launch_bounds__(256) void proj_mfma(
    const float* __restrict__ x,
    const float* __restrict__ Qw, const float* __restrict__ Qb,
    const float* __restrict__ Kw, const float* __restrict__ Kb,
    const float* __restrict__ Vw, const float* __restrict__ Vb,
    unsigned char* __restrict__ qws, unsigned char* __restrict__ kws,
    float* __restrict__ vout)
{
    const int t    = threadIdx.x;
    const int w    = t >> 6;        // wave 0..3
    const int lane = t & 63;
    const int tn   = lane & 15;
    const int g    = lane >> 4;     // 0..3

    const int mat = blockIdx.y;
    const float* W    = (mat == 0) ? Qw : (mat == 1) ? Kw : Vw;
    const float* bias = (mat == 0) ? Qb : (mat == 1) ? Kb : Vb;
    unsigned char* qk_dst = (mat == 0) ? qws : kws;
    const float qsc = (mat == 0) ? 0.25f : 1.0f;    // 1/sqrt(DK) folded into q

    short8v bf[8][2];
    float bv[8];
    #pragma unroll
    for (int a0t = 0; a0t < 8; ++a0t) {
        bv[a0t] = bias[a0t * 16 + tn];
        const float4* wr = (const float4*)(W + (size_t)(a0t * 16 + tn) * F);
        bf[a0t][0] = cvt8(wr[g * 2],     wr[g * 2 + 1]);
        bf[a0t][1] = cvt8(wr[8 + g * 2], wr[8 + g * 2 + 1]);
    }

    #pragma unroll
    for (int rt = 0; rt < 2; ++rt) {
        const int m0t = blockIdx.x * 128 + rt * 64 + w * 16;
        if (m0t >= TOTAL) break;

        const float4* xr = (const float4*)(x + (size_t)(m0t + tn) * F);
        short8v a0 = cvt8(xr[g * 2],     xr[g * 2 + 1]);
        short8v a1 = cvt8(xr[8 + g * 2], xr[8 + g * 2 + 1]);

        f32x4 acc[8];
        #pragma unroll
        for (int a0t = 0; a0t < 8; ++a0t) {
            acc[a0t][0] = bv[a0t]; acc[a0t][1] = bv[a0t];
            acc[a0t][2] = bv[a0t]; acc[a0t][3] = bv[a0t];
        }
        #pragma unroll
        for (int a0t = 0; a0t < 8; ++a0t) {
            acc[a0t] = __builtin_amdgcn_mfma_f32_16x16x32_bf16(a0, bf[a0t][0], acc[a0t], 0, 0, 0);
            acc[a0t] = __builtin_amdgcn_mfma_f32_16x16x32_bf16(a1, bf[a0t][1], acc[a0t], 0, 0, 0);
        }

        if (mat < 2) {
            #pragma unroll
            for (int r = 0; r < 4; ++r) {
                const int node = m0t + g * 4 + r;
                unsigned u0 = (unsigned)__builtin_amdgcn_cvt_pk_fp8_f32(
                                  acc[0][r] * qsc, acc[1][r] * qsc, 0, false);
                u0 = (unsigned)__builtin_amdgcn_cvt_pk_fp8_f32(
                                  acc[2][r] * qsc, acc[3][r] * qsc, (int)u0, true);
                unsigned u1 = (unsigned)__builtin_amdgcn_cvt_pk_fp8_f32(
                                  acc[4][r] * qsc, acc[5][r] * qsc, 0, false);
                u1 = (unsigned)__builtin_amdgcn_cvt_pk_fp8_f32(
                                  acc[6][r] * qsc, acc[7][r] * qsc, (int)u1, true);
                *(uint2*)(qk_dst + (size_t)node * DA + tn * 8) = make_uint2(u0, u1);
            }
        } else {
            #pragma unroll
            for (int r = 0; r < 4; ++r) {
                const int node = m0t + g * 4 + r;
                float* vb = vout + (size_t)node * DA + tn * 8;
                *(float4*)vb       = make_float4(acc[0][r], acc[1][r], acc[2][r], acc[3][r]);
                *(float4*)(vb + 4) = make_float4(acc[4][r], acc[5][r], acc[6][r], acc[7][r]);
            }
        }
    }
}

// ---------------------------------------------------------------------------
// K2: cooperative fp8 gather + dot + fused softmax partials.
// 4 lanes per edge; lane i reads bytes [16i,16i+16) and [64+16i, +16) of each
// 128B row -> one 64B line per 4-lane group per load instr, 4 loads/edge-lane.
// dword at byte o covers heads (o%8)..(o%8)+3. 2-level shfl_xor -> head sums.
// grid = (B, NBLK): linear id % 4 == b -> each XCD's L2 holds one b (2.56MB).
// ---------------------------------------------------------------------------
__global__ __launch_bounds__(256) void gather_dot_sm(
    const unsigned char* __restrict__ qws, const unsigned char* __restrict__ kws,
    const int* __restrict__ edge, float* __restrict__ att,
    float2* __restrict__ partials)
{
    const int b   = blockIdx.x;
    const int blk = blockIdx.y;
    const int t = threadIdx.x;
    const int w = t >> 6, lane = t & 63;
    const int g = lane >> 2, i = lane & 3;

    const unsigned char* qb = qws + (size_t)b * N * DA;
    const unsigned char* kb = kws + (size_t)b * N * DA;
    float* attb = att + (size_t)b * E * H;

    const int ew0 = blk * EPB + w * (EPB / 4);   // wave's edge base

    float ma0 = -3.0e38f, sa0 = 0.f, ma1 = -3.0e38f, sa1 = 0.f;

    #pragma unroll 1
    for (int r = 0; r < EPB / 4 / 16; ++r) {     // 8 rounds of 16 edges
        const int el = ew0 + r * 16 + g;
        const bool valid = el < E;
        const int eidx = valid ? el : 0;
        const int s = edge[eidx];
        const int d = edge[E + eidx];
        const uint4* qp = (const uint4*)(qb + (size_t)s * DA) + i;
        const uint4* kp = (const uint4*)(kb + (size_t)d * DA) + i;
        uint4 q0 = qp[0], q1 = qp[4];
        uint4 k0 = kp[0], k1 = kp[4];

        f32x2 o01 = {0.f, 0.f}, o23 = {0.f, 0.f}, o45 = {0.f, 0.f}, o67 = {0.f, 0.f};
        fp8dot(q0.x, k0.x, o01, o23);
        fp8dot(q0.y, k0.y, o45, o67);
        fp8dot(q0.z, k0.z, o01, o23);
        fp8dot(q0.w, k0.w, o45, o67);
        fp8dot(q1.x, k1.x, o01, o23);
        fp8dot(q1.y, k1.y, o45, o67);
        fp8dot(q1.z, k1.z, o01, o23);
        fp8dot(q1.w, k1.w, o45, o67);

        // reduce across the 4 lanes of the edge group
        #pragma unroll
        for (int off = 1; off <= 2; off <<= 1) {
            o01[0] += __shfl_xor(o01[0], off);  o01[1] += __shfl_xor(o01[1], off);
            o23[0] += __shfl_xor(o23[0], off);  o23[1] += __shfl_xor(o23[1], off);
            o45[0] += __shfl_xor(o45[0], off);  o45[1] += __shfl_xor(o45[1], off);
            o67[0] += __shfl_xor(o67[0], off);  o67[1] += __shfl_xor(o67[1], off);
        }

        f32x2 pp = (i == 0) ? o01 : (i == 1) ? o23 : (i == 2) ? o45 : o67;
        if (valid) {
            *(f32x2*)(attb + (size_t)el * H + 2 * i) = pp;
            float p0 = pp[0], p1 = pp[1];
            if (p0 > ma0) { sa0 = sa0 * __expf(ma0 - p0) + 1.f; ma0 = p0; }
            else          { sa0 += __expf(p0 - ma0); }
            if (p1 > ma1) { sa1 = sa1 * __expf(ma1 - p1) + 1.f; ma1 = p1; }
            else          { sa1 += __expf(p1 - ma1); }
        }
    }

    // wave-level combine across the 16 groups (lanes with equal i)
    #pragma unroll
    for (int off = 4; off <= 32; off <<= 1) {
        float m2 = __shfl_xor(ma0, off), s2 = __shfl_xor(sa0, off);
        ocomb(ma0, sa0, m2, s2);
        m2 = __shfl_xor(ma1, off); s2 = __shfl_xor(sa1, off);
        ocomb(ma1, sa1, m2, s2);
    }

    __shared__ float4 red[4][4];
    if (g == 0) red[w][i] = make_float4(ma0, sa0, ma1, sa1);
    __syncthreads();
    if (t < 4) {
        float m0f = -3.0e38f, s0f = 0.f, m1f = -3.0e38f, s1f = 0.f;
        #pragma unroll
        for (int ww = 0; ww < 4; ++ww) {
            float4 v = red[ww][t];
            ocomb(m0f, s0f, v.x, v.y);
            ocomb(m1f, s1f, v.z, v.w);
        }
        partials[((size_t)b * H + 2 * t)     * NBLK + blk] = make_float2(m0f, s0f);
        partials[((size_t)b * H + 2 * t + 1) * NBLK + blk] = make_float2(m1f, s1f);
    }
}

// ---------------------------------------------------------------------------
// K3: combine NBLK partials per (b,h) -> (M, 1/S). One wave per (b,h).
// ---------------------------------------------------------------------------
__global__ __launch_bounds__(64) void softmax_final(
    const float2* __restrict__ partials, float2* __restrict__ MS)
{
    const int bh = blockIdx.x;
    const int t = threadIdx.x;
    float m = -3.0e38f, s = 0.f;
    for (int c = t; c < NBLK; c += 64) {
        float2 p = partials[(size_t)bh * NBLK + c];
        ocomb(m, s, p.x, p.y);
    }
    #pragma unroll
    for (int off = 1; off < 64; off <<= 1) {
        float m2 = __shfl_xor(m, off), s2 = __shfl_xor(s, off);
        ocomb(m, s, m2, s2);
    }
    if (t == 0) MS[bh] = make_float2(m, 1.0f / s);
}

// ---------------------------------------------------------------------------
// K4: in-place normalize: att = exp(p - M) * (1/S). grid (B, E*H/2048).
// Thread handles 8 consecutive floats (heads 0-3 then 4-7).
// ---------------------------------------------------------------------------
__global__ __launch_bounds__(256) void softmax_norm(
    float* __restrict__ att, const float2* __restrict__ MS)
{
    const int b = blockIdx.x;
    const float2* ms = MS + b * H;
    float* p = att + (size_t)b * (E * H) + (size_t)blockIdx.y * 2048 + threadIdx.x * 8;
    float4 lo = *(float4*)p;
    float4 hi = *(float4*)(p + 4);
    lo.x = __expf(lo.x - ms[0].x) * ms[0].y;
    lo.y = __expf(lo.y - ms[1].x) * ms[1].y;
    lo.z = __expf(lo.z - ms[2].x) * ms[2].y;
    lo.w = __expf(lo.w - ms[3].x) * ms[3].y;
    hi.x = __expf(hi.x - ms[4].x) * ms[4].y;
    hi.y = __expf(hi.y - ms[5].x) * ms[5].y;
    hi.z = __expf(hi.z - ms[6].x) * ms[6].y;
    hi.w = __expf(hi.w - ms[7].x) * ms[7].y;
    *(float4*)p       = lo;
    *(float4*)(p + 4) = hi;
}

extern "C" void kernel_launch(void* const* d_in, const int* in_sizes, int n_in,
                              void* d_out, int out_size, void* d_ws, size_t ws_size,
                              hipStream_t stream)
{
    const float* x  = (const float*)d_in[0];
    const float* Qw = (const float*)d_in[1];
    const float* Qb = (const float*)d_in[2];
    const float* Kw = (const float*)d_in[3];
    const float* Kb = (const float*)d_in[4];
    const float* Vw = (const float*)d_in[5];
    const float* Vb = (const float*)d_in[6];
    const int*   edge = (const int*)d_in[7];

    float* out  = (float*)d_out;
    float* att  = out;                                // B*E*H
    float* vout = out + (size_t)B * E * H;            // B*N*DK*H

    char* w = (char*)d_ws;
    unsigned char* qws = (unsigned char*)w;                       // 5.12 MB fp8
    unsigned char* kws = qws + (size_t)B * N * DA;                // 5.12 MB fp8
    float2* partials = (float2*)(w + 2 * (size_t)B * N * DA);     // ~80 KB
    float2* MS = partials + (size_t)B * H * NBLK;

    hipLaunchKernelGGL(proj_mfma, dim3((TOTAL + 127) / 128, 3), dim3(256), 0, stream,
                       x, Qw, Qb, Kw, Kb, Vw, Vb, qws, kws, vout);
    hipLaunchKernelGGL(gather_dot_sm, dim3(B, NBLK), dim3(256), 0, stream,
                       qws, kws, edge, att, partials);
    hipLaunchKernelGGL(softmax_final, dim3(B * H), dim3(64), 0, stream,
                       partials, MS);
    hipLaunchKernelGGL(softmax_norm, dim3(B, (E * H) / 2048), dim3(256), 0, stream,
                       att, MS);
}